// Round 1
// baseline (465.313 us; speedup 1.0000x reference)
//
#include <hip/hip_runtime.h>
#include <hip/hip_bf16.h>
#include <stdint.h>

#define NTOK 49
#define DIMC 128
#define NHEAD 4
#define SCALE 0.17677669529663687f

typedef __bf16 bf16;
typedef __bf16 bf16x8 __attribute__((ext_vector_type(8)));
typedef __bf16 bf16x4 __attribute__((ext_vector_type(4)));
typedef float  f32x4  __attribute__((ext_vector_type(4)));
typedef short  s16x4  __attribute__((ext_vector_type(4)));

// ---- LDS layout (bf16 elems), total 17920 elems = 35840 B -> 4 blocks/CU ----
// K  @0   : rows [h*64+tok] stride 36 (K[tok][d], transpose-stored)
// VT @9216: rows [h*32+d]  stride 68 (V^T[d][tok], transpose-stored)
// Q, P, O^T never touch LDS: the 16x16x16 MFMA B-fragment layout
// (k=quad*4+i, col=ln15) equals the C layout (row=quad*4+r, col=ln15),
// so each stage's C packs directly into the next stage's B operand.
#define QK_S 36
#define VT_S 68
#define VT_OFF 9216
#define SM_ELEMS 17920

// d_ws layout (bytes): comb bf16 [64][64][4][64] @0 (2 MB);
// qkvw bf16 @2097152 (98304 B); projw bf16 @2195456 (32768 B)
#define WS_QKVW_OFF 2097152
#define WS_PROJW_OFF 2195456

__device__ __forceinline__ f32x4 mfmaK32(bf16x8 a, bf16x8 b, f32x4 c) {
  return __builtin_amdgcn_mfma_f32_16x16x32_bf16(a, b, c, 0, 0, 0);
}
__device__ __forceinline__ f32x4 mfmaK16(bf16x4 a, bf16x4 b, f32x4 c) {
#if __has_builtin(__builtin_amdgcn_mfma_f32_16x16x16bf16_1k)
  return __builtin_amdgcn_mfma_f32_16x16x16bf16_1k(*(s16x4*)&a, *(s16x4*)&b, c,
                                                   0, 0, 0);
#else
  f32x4 d;
  asm("v_mfma_f32_16x16x16_bf16 %0, %1, %2, %3"
      : "=v"(d) : "v"(a), "v"(b), "v"(c));
  return d;
#endif
}
__device__ __forceinline__ bf16x8 cvt8(const float* __restrict__ p) {
  f32x4 a = *(const f32x4*)p;
  f32x4 c = *(const f32x4*)(p + 4);
  bf16x8 r;
#pragma unroll
  for (int j = 0; j < 4; ++j) { r[j] = (bf16)a[j]; r[4 + j] = (bf16)c[j]; }
  return r;
}

// ---------------- prologue: build comb table + bf16 weights in d_ws ----------
__global__ __launch_bounds__(256)
void prep(const float* __restrict__ maskg, const float* __restrict__ rpb,
          const int* __restrict__ rel, const float* __restrict__ qkvw,
          const float* __restrict__ projw, bf16* __restrict__ comb,
          bf16* __restrict__ qkvw_b, bf16* __restrict__ projw_b) {
  int id = blockIdx.x * 256 + threadIdx.x;
  if (id < 64 * 64 * 4 * 64) {
    // comb[win][n][h][m] = mask[win][n][m] + rpb[rel[n][m]][h], -30000 at pads
    int m = id & 63, h = (id >> 6) & 3, n = (id >> 8) & 63, win = id >> 14;
    float v = -30000.0f;
    if (n < NTOK && m < NTOK)
      v = maskg[((size_t)win * NTOK + n) * NTOK + m] + rpb[rel[n * NTOK + m] * 4 + h];
    comb[id] = (bf16)v;
  } else {
    int t = id - 64 * 64 * 4 * 64;          // 0..65535
    if (t < 384 * 128) qkvw_b[t] = (bf16)qkvw[t];
    else               projw_b[t - 384 * 128] = (bf16)projw[t - 384 * 128];
  }
}

// ---------------- main kernel: one window per block, 4 waves ----------------
__global__ __launch_bounds__(256, 4)
void winattn(const float* __restrict__ xg, const float* __restrict__ qkvb,
             const float* __restrict__ projb, const bf16* __restrict__ comb,
             const bf16* __restrict__ qkvw_b, const bf16* __restrict__ projw_b,
             float* __restrict__ out) {
  __shared__ bf16 sm[SM_ELEMS];

  const int b    = blockIdx.x;
  const int tid  = threadIdx.x;
  const int w    = tid >> 6;        // wave id: head owned in k/v; token group in q/phase2
  const int lane = tid & 63;
  const int ln15 = lane & 15;
  const int quad = lane >> 4;
  const int nq   = w * 16 + ln15;   // this lane's query column (phase 2)

  // ---- x fragments straight from global (L1-backed; rows>=49 clamped; pad
  // rows are neutralized downstream by comb=-30000 and the output guard) ----
  const float* xb = xg + (size_t)b * (NTOK * DIMC);
  bf16x8 xf[4][4];
#pragma unroll
  for (int mt = 0; mt < 4; ++mt) {
    int tok = mt * 16 + ln15;
    const float* xr = xb + (tok < NTOK ? tok : (NTOK - 1)) * DIMC;
#pragma unroll
    for (int ks = 0; ks < 4; ++ks)
      xf[mt][ks] = cvt8(&xr[ks * 32 + quad * 8]);
  }

  // ---- k (head w, all 64 tokens): C[d][tok] scatter-stored as K[tok][d] ----
#pragma unroll
  for (int t = 0; t < 2; ++t) {
    const int j0 = DIMC + w * 32 + t * 16;
    bf16x8 wf[4];
#pragma unroll
    for (int ks = 0; ks < 4; ++ks)
      wf[ks] = *(const bf16x8*)&qkvw_b[(size_t)(j0 + ln15) * DIMC + ks * 32 + quad * 8];
    f32x4 b4 = *(const f32x4*)&qkvb[j0 + quad * 4];
#pragma unroll
    for (int mt = 0; mt < 4; ++mt) {
      f32x4 acc = (f32x4)(0.0f);
#pragma unroll
      for (int ks = 0; ks < 4; ++ks) acc = mfmaK32(wf[ks], xf[mt][ks], acc);
      bf16x4 pk;
#pragma unroll
      for (int r = 0; r < 4; ++r) pk[r] = (bf16)(acc[r] + b4[r]);
      *(bf16x4*)&sm[(w * 64 + mt * 16 + ln15) * QK_S + t * 16 + quad * 4] = pk;
    }
  }

  // ---- v (head w): C[tok][d] scatter-stored as VT[d][tok] ----
#pragma unroll
  for (int t = 0; t < 2; ++t) {
    const int j0 = 2 * DIMC + w * 32 + t * 16;
    bf16x8 wf[4];
#pragma unroll
    for (int ks = 0; ks < 4; ++ks)
      wf[ks] = *(const bf16x8*)&qkvw_b[(size_t)(j0 + ln15) * DIMC + ks * 32 + quad * 8];
    float bv = qkvb[j0 + ln15];
#pragma unroll
    for (int mt = 0; mt < 4; ++mt) {
      f32x4 acc = (f32x4)(0.0f);
#pragma unroll
      for (int ks = 0; ks < 4; ++ks) acc = mfmaK32(xf[mt][ks], wf[ks], acc);
      bf16x4 pk;
#pragma unroll
      for (int r = 0; r < 4; ++r) pk[r] = (bf16)(acc[r] + bv);
      *(bf16x4*)&sm[VT_OFF + (w * 32 + t * 16 + ln15) * VT_S + mt * 16 + quad * 4] = pk;
    }
  }

  // ---- q: ALL 128 rows for this wave's own 16 tokens; stays in registers.
  // C[j=quad*4+r][tok=ln15] with tok==nq is directly the 16x16x16 B-frag
  // B[k=quad*4+i][col=ln15] for k-tile tq. Fresh xq loads (L1-hot) avoid the
  // runtime-indexed xf[w] (would go to scratch, rule #20) and let xf die. ----
  bf16x4 qw[8];
  {
    const float* xqr = xb + (nq < NTOK ? nq : (NTOK - 1)) * DIMC;
    bf16x8 xq[4];
#pragma unroll
    for (int ks = 0; ks < 4; ++ks) xq[ks] = cvt8(&xqr[ks * 32 + quad * 8]);
#pragma unroll
    for (int tq = 0; tq < 8; ++tq) {
      const int j0 = tq * 16;
      f32x4 acc = (f32x4)(0.0f);
#pragma unroll
      for (int ks = 0; ks < 4; ++ks) {
        bf16x8 wf = *(const bf16x8*)&qkvw_b[(size_t)(j0 + ln15) * DIMC + ks * 32 + quad * 8];
        acc = mfmaK32(wf, xq[ks], acc);
      }
      f32x4 b4 = *(const f32x4*)&qkvb[j0 + quad * 4];
#pragma unroll
      for (int r = 0; r < 4; ++r) qw[tq][r] = (bf16)((acc[r] + b4[r]) * SCALE);
    }
  }

  __syncthreads();   // K, VT visible to all waves — the ONLY barrier

  // ---- combined bias (mask+rpb) for all heads: 16x 8B loads (L2) ----
  const bf16* cbase = comb + ((size_t)(b & 63) * 64 + nq) * (4 * 64);
  bf16x4 combv[NHEAD][4];
#pragma unroll
  for (int h = 0; h < NHEAD; ++h)
#pragma unroll
    for (int mt = 0; mt < 4; ++mt)
      combv[h][mt] = *(const bf16x4*)&cbase[h * 64 + mt * 16 + quad * 4];

  // ---- phase 2: per-head attention, fully in registers except K/VT reads ----
  bf16x4 ow[8];      // O^T bf16, B-frags for proj (k-tile = 2h+dt)
#pragma unroll
  for (int h = 0; h < NHEAD; ++h) {
    // S^T tile: A = K[m][d] (b64 LDS reads), B = qw -> C[m%16][nq]
    f32x4 st[4];
#pragma unroll
    for (int mt = 0; mt < 4; ++mt) {
      const bf16* kr = &sm[(h * 64 + mt * 16 + ln15) * QK_S + quad * 4];
      bf16x4 k0 = *(const bf16x4*)kr;          // d = quad*4+i
      bf16x4 k1 = *(const bf16x4*)(kr + 16);   // d = 16+quad*4+i
      st[mt] = mfmaK16(k1, qw[2 * h + 1], mfmaK16(k0, qw[2 * h], (f32x4)(0.0f)));
    }
    // exp(logit+bias) without max-sub (bounded; clamp 60; -30000 underflows->0)
    float ssum = 0.0f;
#pragma unroll
    for (int mt = 0; mt < 4; ++mt)
#pragma unroll
      for (int r = 0; r < 4; ++r) {
        float v = fminf(st[mt][r] + (float)combv[h][mt][r], 60.0f);
        float p = __expf(v);
        st[mt][r] = p;
        ssum += p;
      }
    // P^T C-layout == PV B-frag layout: pack in-register, no LDS round trip
    bf16x4 pw[4];
#pragma unroll
    for (int mt = 0; mt < 4; ++mt)
#pragma unroll
      for (int r = 0; r < 4; ++r) pw[mt][r] = (bf16)st[mt][r];
    ssum += __shfl_xor(ssum, 16);
    ssum += __shfl_xor(ssum, 32);
    // O^T = V^T·P^T : A = VT rows (b64 LDS reads), B = pw
    f32x4 oa[2];
#pragma unroll
    for (int dt = 0; dt < 2; ++dt) {
      const bf16* vr = &sm[VT_OFF + (h * 32 + dt * 16 + ln15) * VT_S + quad * 4];
      f32x4 a = (f32x4)(0.0f);
#pragma unroll
      for (int mt = 0; mt < 4; ++mt)
        a = mfmaK16(*(const bf16x4*)(vr + mt * 16), pw[mt], a);
      oa[dt] = a;
    }
    const float inv = 1.0f / ssum;
#pragma unroll
    for (int dt = 0; dt < 2; ++dt)
#pragma unroll
      for (int r = 0; r < 4; ++r) ow[2 * h + dt][r] = (bf16)(oa[dt][r] * inv);
  }

  // ---- proj GEMM: Y^T = projW·O^T, K=128 as 8 k-tiles of 16; O^T already in
  // B-frag form (ow). Weights: 8B loads, L2-resident, freely hoistable. ----
  f32x4 yacc[8];
#pragma unroll
  for (int jt = 0; jt < 8; ++jt) {
    f32x4 a = (f32x4)(0.0f);
#pragma unroll
    for (int kt = 0; kt < 8; ++kt) {
      bf16x4 aw = *(const bf16x4*)&projw_b[(size_t)(jt * 16 + ln15) * DIMC + kt * 16 + quad * 4];
      a = mfmaK16(aw, ow[kt], a);
    }
    yacc[jt] = a;
  }

  // ---- epilogue: + projb, fp32 16B stores; lane column = token nq ----
  if (nq < NTOK) {
    float* ob = out + (size_t)b * (NTOK * DIMC) + nq * DIMC;
#pragma unroll
    for (int jt = 0; jt < 8; ++jt) {
      f32x4 pbv = *(const f32x4*)&projb[jt * 16 + quad * 4];
      f32x4 y;
#pragma unroll
      for (int r = 0; r < 4; ++r) y[r] = yacc[jt][r] + pbv[r];
      *(f32x4*)&ob[jt * 16 + quad * 4] = y;
    }
  }
}

extern "C" void kernel_launch(void* const* d_in, const int* in_sizes, int n_in,
                              void* d_out, int out_size, void* d_ws, size_t ws_size,
                              hipStream_t stream) {
  const float* x     = (const float*)d_in[0];
  const float* mask  = (const float*)d_in[1];
  const float* qkv_w = (const float*)d_in[2];
  const float* qkv_b = (const float*)d_in[3];
  const float* rpb   = (const float*)d_in[4];
  const float* prj_w = (const float*)d_in[5];
  const float* prj_b = (const float*)d_in[6];
  const int*   rel   = (const int*)d_in[7];
  float* out = (float*)d_out;

  bf16* ws_comb  = (bf16*)d_ws;
  bf16* ws_qkvw  = (bf16*)((char*)d_ws + WS_QKVW_OFF);
  bf16* ws_projw = (bf16*)((char*)d_ws + WS_PROJW_OFF);

  const int B = in_sizes[0] / (NTOK * DIMC);   // 4096
  prep<<<4352, 256, 0, stream>>>(mask, rpb, rel, qkv_w, prj_w,
                                 ws_comb, ws_qkvw, ws_projw);
  winattn<<<B, 256, 0, stream>>>(x, qkv_b, prj_b, ws_comb, ws_qkvw, ws_projw, out);
}